// Round 12
// baseline (315.392 us; speedup 1.0000x reference)
//
#include <hip/hip_runtime.h>

typedef _Float16 f16;
typedef _Float16 f16x8 __attribute__((ext_vector_type(8)));
typedef _Float16 f16x4 __attribute__((ext_vector_type(4)));
typedef float    f32x4 __attribute__((ext_vector_type(4)));
typedef unsigned int u32;
typedef u32 u32x2 __attribute__((ext_vector_type(2)));
typedef u32 u32x4 __attribute__((ext_vector_type(4)));
typedef unsigned short ush;

#define CC 256
#define NN 4096
#define BB 4
#define RSC 17          // combine buffer stride (f32)

union Frag8 { u32x4 u4; f16x8 f; };
union Frag4 { u32x2 u2; f16x4 f; };

static __device__ __forceinline__ u32 pkrtz(float a, float b) {
  auto t = __builtin_amdgcn_cvt_pkrtz(a, b);
  return __builtin_bit_cast(u32, t);
}
static __device__ __forceinline__ ush f2h(float x) {   // RNE
  f16 h = (f16)x;
  return __builtin_bit_cast(ush, h);
}

static __device__ __forceinline__ void gload16(const ush* g, ush* l) {
  __builtin_amdgcn_global_load_lds(
      (const __attribute__((address_space(1))) u32*)g,
      (__attribute__((address_space(3))) u32*)l, 16, 0, 0);
}

#define MFMA32(A, B, C) __builtin_amdgcn_mfma_f32_16x16x32_f16((A), (B), (C), 0, 0, 0)
#define MFMA16(A, B, C) __builtin_amdgcn_mfma_f32_16x16x16f16((A), (B), (C), 0, 0, 0)

// K1: M[c][cp] = sum_o w1[o,c]*w2[o,cp] ; g[cp] = sum_o b1[o]*w2[o,cp]
__global__ void k_prep(const float* __restrict__ w1, const float* __restrict__ w2,
                       const float* __restrict__ b1, float* __restrict__ M,
                       float* __restrict__ g) {
  const int c  = blockIdx.x;
  const int cp = threadIdx.x;
  float acc = 0.f;
#pragma unroll 8
  for (int o = 0; o < CC; ++o)
    acc += w1[o * CC + c] * w2[o * CC + cp];
  M[c * CC + cp] = acc;
  if (c == 0) {
    float ga = 0.f;
    for (int o = 0; o < CC; ++o)
      ga += b1[o] * w2[o * CC + cp];
    g[cp] = ga;
  }
}

// K-cvt: x2 tile -> kimg (swizzled [j][c] LDS byte-image) + vimg (PV-fragment
// order) + r2[b,j] = sum_c g[c]*x2[b,c,j].   (all fp16 RNE)
// K image row j (512B): 16B slot st holds halves c=8s..8s+7 with s = st^(j&7).
__global__ void k_cvt(const float* __restrict__ x2, const float* __restrict__ g,
                      ush* __restrict__ kimg, ush* __restrict__ vimg,
                      float* __restrict__ r2) {
  __shared__ float Xs[256 * 37];
  __shared__ float Ps[32 * 9];
  const int tid = threadIdx.x;
  const int b   = blockIdx.x >> 7;
  const int jt  = blockIdx.x & 127;
  const int j0  = jt << 5;
  const float* x2b = x2 + ((size_t)b << 20);
  {
    const int jf = tid & 7, c0 = tid >> 3;
#pragma unroll
    for (int m = 0; m < 8; ++m) {
      int c = c0 + (m << 5);
      float4 v = *(const float4*)(x2b + ((size_t)c << 12) + j0 + (jf << 2));
      *(float4*)(Xs + c * 37 + (jf << 2)) = v;
    }
  }
  __syncthreads();
  const size_t tile = ((size_t)blockIdx.x) << 13;   // halves
  {
    ush* kp = kimg + tile;
#pragma unroll
    for (int m = 0; m < 4; ++m) {
      int idx = tid + (m << 8);
      int j = idx >> 5, st = idx & 31;
      int s = st ^ (j & 7);
      u32 hw[4];
#pragma unroll
      for (int k = 0; k < 4; ++k) {
        float a  = Xs[(8 * s + 2 * k) * 37 + j];
        float c2 = Xs[(8 * s + 2 * k + 1) * 37 + j];
        hw[k] = (u32)f2h(a) | ((u32)f2h(c2) << 16);
      }
      u32x4 v; v.x = hw[0]; v.y = hw[1]; v.z = hw[2]; v.w = hw[3];
      *(u32x4*)(kp + (idx << 3)) = v;
    }
  }
  {
    ush* vp = vimg + tile;
#pragma unroll
    for (int mm = 0; mm < 4; ++mm) {
      int e = tid + (mm << 8);
      int lqe = e & 15, ge = (e >> 4) & 3, he = (e >> 6) & 1, me = e >> 7;
      int c0 = lqe + (me << 5);
      int q0 = (he << 4) + (ge << 2);
      const float* r0 = Xs + c0 * 37 + q0;
      const float* r1 = Xs + (c0 + 16) * 37 + q0;
      u32x4 v;
      v.x = (u32)f2h(r0[0]) | ((u32)f2h(r0[1]) << 16);
      v.y = (u32)f2h(r0[2]) | ((u32)f2h(r0[3]) << 16);
      v.z = (u32)f2h(r1[0]) | ((u32)f2h(r1[1]) << 16);
      v.w = (u32)f2h(r1[2]) | ((u32)f2h(r1[3]) << 16);
      *(u32x4*)(vp + (e << 3)) = v;
    }
  }
  {
    const int j = tid & 31, s = tid >> 5;
    float acc = 0.f;
#pragma unroll 8
    for (int k = 0; k < 32; ++k)
      acc += g[(s << 5) + k] * Xs[((s << 5) + k) * 37 + j];
    Ps[j * 9 + s] = acc;
  }
  __syncthreads();
  if (tid < 32) {
    float a = 0.f;
#pragma unroll
    for (int s = 0; s < 8; ++s) a += Ps[tid * 9 + s];
    r2[(b << 12) + j0 + tid] = a;
  }
}

// K3: QT=32, 512-thread blocks: 8 waves = (p:2 i-groups) x (h:2 j-groups) x
// (q:2 c-groups). q-split halves per-wave registers (vacc[8], Vd[4]) ->
// <=128 unified regs/wave -> 4 waves/SIMD -> 16 waves/CU (2 blocks).
// S+softmax duplicated across q (cheap: MFMA pipe was 17% busy).
__launch_bounds__(512, 4)
__global__ void k_attn(const float* __restrict__ x1, const ush* __restrict__ kimg,
                       const ush* __restrict__ vimg, const float* __restrict__ M,
                       const float* __restrict__ r2, float* __restrict__ out) {
  extern __shared__ ush lds[];
  const int tid  = threadIdx.x;
  const int lane = tid & 63;
  const int w    = tid >> 6;
  const int h    = w & 1;          // j-group
  const int q    = (w >> 1) & 1;   // c-group
  const int p    = w >> 2;         // i-group
  const int g    = lane >> 4;
  const int lq   = lane & 15;

  int bid = (int)blockIdx.x;
  bid = (bid & 7) * 64 + (bid >> 3);        // bijective XCD swizzle (512 = 8*64)
  const int b  = bid >> 7;
  const int i0 = (bid & 127) << 5;

  const float* x1b = x1 + ((size_t)b << 20);

  // ---- Q-prep (VALU f32, two 16-i passes); x1f @0 (18KB), Qhi @ byte 18432 ----
  float* x1f = (float*)lds;                 // [256][18] f32
  ush* Qhi = lds + 9216;                    // [32][256] halves (byte 18432..34816)
  for (int ih = 0; ih < 2; ++ih) {
    {
      const int jf = tid & 3, c0 = tid >> 2;
#pragma unroll
      for (int m = 0; m < 2; ++m) {
        int c = c0 + (m << 7);
        float4 v = *(const float4*)(x1b + ((size_t)c << 12) + i0 + (ih << 4) + (jf << 2));
        *(float4*)(x1f + c * 18 + (jf << 2)) = v;
      }
    }
    __syncthreads();
    {
      const int tc = tid & 63, iq = tid >> 6;   // i = 16ih + 2iq + e
      float acc[4][2];
#pragma unroll
      for (int a = 0; a < 4; ++a) { acc[a][0] = 0.f; acc[a][1] = 0.f; }
#pragma unroll 4
      for (int c = 0; c < CC; ++c) {
        float4 mv = *(const float4*)(M + c * CC + (tc << 2));
        float x0  = x1f[c * 18 + (iq << 1)];
        float x1v = x1f[c * 18 + (iq << 1) + 1];
        acc[0][0] += mv.x * x0; acc[0][1] += mv.x * x1v;
        acc[1][0] += mv.y * x0; acc[1][1] += mv.y * x1v;
        acc[2][0] += mv.z * x0; acc[2][1] += mv.z * x1v;
        acc[3][0] += mv.w * x0; acc[3][1] += mv.w * x1v;
      }
#pragma unroll
      for (int e = 0; e < 2; ++e) {
        int i = (ih << 4) + (iq << 1) + e;
        u32 h0 = (u32)f2h(acc[0][e]) | ((u32)f2h(acc[1][e]) << 16);
        u32 h1 = (u32)f2h(acc[2][e]) | ((u32)f2h(acc[3][e]) << 16);
        u32x2 hw; hw.x = h0; hw.y = h1;
        *(u32x2*)(Qhi + (i << 8) + (tc << 2)) = hw;
      }
    }
    __syncthreads();
  }

  // ---- preload Q fragments (wave (p,h,q): Q rows 16p..16p+15) ----
  Frag8 QBh[8];
  {
    const int qoff = ((p << 4) + lq) << 8;
#pragma unroll
    for (int cs = 0; cs < 8; ++cs)
      QBh[cs].u4 = *(const u32x4*)(Qhi + qoff + (cs << 5) + (g << 3));
  }
  __syncthreads();

  // ---- main flash loop ----
  f32x4 vacc[8];
#pragma unroll
  for (int n = 0; n < 8; ++n) vacc[n] = (f32x4){0.f, 0.f, 0.f, 0.f};
  float m_run = -3.0e38f, l_run = 0.f;

  const int sx   = lq & 7;
  const int koff = ((h << 4) + lq) << 8;    // K row (halves)
  const float* r2p = r2 + (b << 12) + (h << 4) + (g << 2);
  const size_t bt = (size_t)(b << 7);
  // wave q reads vimg entries 4q..4q+3: halves (4q+m)*1024 + h*512 + g*128 + lq*8
  const ush* vbase = vimg + (bt << 13) + (q << 12) + (h << 9) + (g << 7) + (lq << 3);

  Frag8 Vd[4];
  float4 r2a, r2b;

  // prologue: K(0) DMA (2/thread) -> buf0, V(0) 4 loads, r2(0); wait K only.
  {
    const ush* gk = kimg + (bt << 13);
    gload16(gk + ((size_t)tid << 3),         lds + (tid << 3));
    gload16(gk + ((size_t)(tid + 512) << 3), lds + ((tid + 512) << 3));
    __builtin_amdgcn_sched_barrier(0);
#pragma unroll
    for (int m = 0; m < 4; ++m)
      Vd[m].u4 = *(const u32x4*)(vbase + (m << 10));
    r2a = *(const float4*)(r2p);
  }
  __builtin_amdgcn_sched_barrier(0);
  asm volatile("s_waitcnt vmcnt(5)" ::: "memory");
  __builtin_amdgcn_sched_barrier(0);
  __builtin_amdgcn_s_barrier();

  auto body = [&](int t, float4& r2c, float4& r2n) {
    const int cur = (t & 1) << 13;           // halves: buffers at 0 / 16KB
    if (t + 1 < 128) {
      const int nxt = cur ^ 8192;
      const ush* gk = kimg + ((bt + t + 1) << 13);
      gload16(gk + ((size_t)tid << 3),         lds + nxt + (tid << 3));
      gload16(gk + ((size_t)(tid + 512) << 3), lds + nxt + ((tid + 512) << 3));
    }
    __builtin_amdgcn_sched_barrier(0);
    const ush* kb = lds + cur;

    // S^T = K·Q (duplicated across q), 2 chains
    f32x4 a1 = {0.f,0.f,0.f,0.f}, a2 = {0.f,0.f,0.f,0.f};
#pragma unroll
    for (int cs = 0; cs < 8; cs += 2) {
      int st1 = ((cs << 2) + g) ^ sx;
      int st2 = (((cs + 1) << 2) + g) ^ sx;
      Frag8 A1; A1.u4 = *(const u32x4*)(kb + koff + (st1 << 3));
      Frag8 A2; A2.u4 = *(const u32x4*)(kb + koff + (st2 << 3));
      a1 = MFMA32(A1.f, QBh[cs].f, a1);
      a2 = MFMA32(A2.f, QBh[cs + 1].f, a2);
    }

    // wait V(t)+r2(t); K(t+1)'s 2 DMAs stay in flight
    if (t + 1 < 128) {
      asm volatile("s_waitcnt vmcnt(2)" ::: "memory");
    } else {
      asm volatile("s_waitcnt vmcnt(0)" ::: "memory");
    }
    __builtin_amdgcn_sched_barrier(0);

    // online softmax (rows i = 16p+lq; j = 32t + 16h + 4g + r)
    float s0 = a1[0] + a2[0] + r2c.x, s1 = a1[1] + a2[1] + r2c.y;
    float s2 = a1[2] + a2[2] + r2c.z, s3 = a1[3] + a2[3] + r2c.w;
    float mx = fmaxf(fmaxf(s0, s1), fmaxf(s2, s3));
    mx = fmaxf(mx, __shfl_xor(mx, 16));
    mx = fmaxf(mx, __shfl_xor(mx, 32));
    float mn = fmaxf(m_run, mx);
    int stb = (mn == m_run) ? 1 : 0;
    float scl = __expf(m_run - mn);
    float p0 = __expf(s0 - mn), p1 = __expf(s1 - mn);
    float p2 = __expf(s2 - mn), p3 = __expf(s3 - mn);
    float rs = p0 + p1 + p2 + p3;
    rs += __shfl_xor(rs, 16);
    rs += __shfl_xor(rs, 32);
    l_run = l_run * scl + rs;
    m_run = mn;

    Frag4 Pf;
    Pf.u2.x = pkrtz(p0, p1);
    Pf.u2.y = pkrtz(p2, p3);

    if (!__all(stb)) {
#pragma unroll
      for (int n = 0; n < 8; ++n) {
        vacc[n][0] *= scl; vacc[n][1] *= scl;
        vacc[n][2] *= scl; vacc[n][3] *= scl;
      }
    }
#pragma unroll
    for (int m = 0; m < 4; ++m) {
      Frag4 Va, Vb;
      Va.u2.x = Vd[m].u4.x; Va.u2.y = Vd[m].u4.y;     // n = 2m
      Vb.u2.x = Vd[m].u4.z; Vb.u2.y = Vd[m].u4.w;     // n = 2m+1
      vacc[2 * m]     = MFMA16(Va.f, Pf.f, vacc[2 * m]);
      vacc[2 * m + 1] = MFMA16(Vb.f, Pf.f, vacc[2 * m + 1]);
    }

    if (t + 1 < 128) {
      // prefetch V(t+1)+r2(t+1); drain K(t+1) only; cross-wave barrier
      const ush* vt_ = vbase + ((size_t)(t + 1) << 13);
#pragma unroll
      for (int m = 0; m < 4; ++m)
        Vd[m].u4 = *(const u32x4*)(vt_ + (m << 10));
      r2n = *(const float4*)(r2p + ((t + 1) << 5));
      __builtin_amdgcn_sched_barrier(0);
      asm volatile("s_waitcnt vmcnt(5)" ::: "memory");
      __builtin_amdgcn_sched_barrier(0);
      __builtin_amdgcn_s_barrier();
    }
  };

  for (int tt = 0; tt < 128; tt += 2) {
    body(tt,     r2a, r2b);
    body(tt + 1, r2b, r2a);
  }

  // ---- merge j-halves, normalize, store ----
  __syncthreads();
  float* Cmb = (float*)lds;                 // [2 p][256 c][17] f32 = 34816B
  float* Msm = (float*)(lds + 17408);       // byte 34816: [2 p][2 h][16]
  float* Lsm = Msm + 64;
  if (g == 0 && q == 0) {
    Msm[p * 32 + h * 16 + lq] = m_run;
    Lsm[p * 32 + h * 16 + lq] = l_run;
  }
  __syncthreads();
  float mo  = Msm[p * 32 + (1 - h) * 16 + lq];
  float lo2 = Lsm[p * 32 + (1 - h) * 16 + lq];
  float mt    = fmaxf(m_run, mo);
  float aSelf = __expf(m_run - mt);
  float l_tot = l_run * aSelf + lo2 * __expf(mo - mt);

  if (h == 0) {
    float* cb_ = Cmb + p * (CC * RSC);
#pragma unroll
    for (int n = 0; n < 8; ++n)
#pragma unroll
      for (int r = 0; r < 4; ++r) {
        int c = (q << 7) + (n << 4) + (g << 2) + r;
        cb_[c * RSC + lq] = vacc[n][r] * aSelf;
      }
  }
  __syncthreads();
  if (h == 1) {
    const float* cb_ = Cmb + p * (CC * RSC);
    float inv = 1.f / l_tot;
    float* ob = out + ((size_t)b << 20) + i0 + (p << 4) + lq;
#pragma unroll
    for (int n = 0; n < 8; ++n)
#pragma unroll
      for (int r = 0; r < 4; ++r) {
        int c = (q << 7) + (n << 4) + (g << 2) + r;
        ob[(size_t)c << 12] = (vacc[n][r] * aSelf + cb_[c * RSC + lq]) * inv;
      }
  }
}

extern "C" void kernel_launch(void* const* d_in, const int* in_sizes, int n_in,
                              void* d_out, int out_size, void* d_ws, size_t ws_size,
                              hipStream_t stream) {
  const float* x1 = (const float*)d_in[0];
  const float* x2 = (const float*)d_in[1];
  const float* w1 = (const float*)d_in[2];
  const float* b1 = (const float*)d_in[3];
  const float* w2 = (const float*)d_in[4];
  // b2 (d_in[5]) contributes only row-constant energy terms -> cancels in softmax.

  float* M  = (float*)d_ws;            // 256KB
  float* g  = M + 65536;
  float* r2 = g + 256;                 // 64KB
  ush* kimg = (ush*)(r2 + 16384);      // 8MB, per-tile 16KB LDS byte-images
  ush* vimg = kimg + 4194304;          // 8MB, per-tile PV-fragment-ordered fp16
  float* outp = (float*)d_out;

  const int LDS_BYTES = 35328;
  (void)hipFuncSetAttribute((const void*)k_attn,
                            hipFuncAttributeMaxDynamicSharedMemorySize, LDS_BYTES);

  k_prep<<<CC, 256, 0, stream>>>(w1, w2, b1, M, g);
  k_cvt<<<BB * (NN / 32), 256, 0, stream>>>(x2, g, kimg, vimg, r2);
  k_attn<<<BB * (NN / 32), 512, LDS_BYTES, stream>>>(x1, kimg, vimg, M, r2, outp);
  (void)in_sizes; (void)n_in; (void)out_size; (void)ws_size;
}

// Round 13
// 272.500 us; speedup vs baseline: 1.1574x; 1.1574x over previous
//
#include <hip/hip_runtime.h>

typedef _Float16 f16;
typedef _Float16 f16x8 __attribute__((ext_vector_type(8)));
typedef _Float16 f16x4 __attribute__((ext_vector_type(4)));
typedef float    f32x4 __attribute__((ext_vector_type(4)));
typedef unsigned int u32;
typedef u32 u32x2 __attribute__((ext_vector_type(2)));
typedef u32 u32x4 __attribute__((ext_vector_type(4)));
typedef unsigned short ush;

#define CC 256
#define NN 4096
#define BB 4
#define RSC 17          // combine buffer stride (f32)

union Frag8 { u32x4 u4; f16x8 f; };
union Frag4 { u32x2 u2; f16x4 f; };

static __device__ __forceinline__ u32 pkrtz(float a, float b) {
  auto t = __builtin_amdgcn_cvt_pkrtz(a, b);
  return __builtin_bit_cast(u32, t);
}
static __device__ __forceinline__ ush f2h(float x) {   // RNE
  f16 h = (f16)x;
  return __builtin_bit_cast(ush, h);
}

static __device__ __forceinline__ void gload16(const ush* g, ush* l) {
  __builtin_amdgcn_global_load_lds(
      (const __attribute__((address_space(1))) u32*)g,
      (__attribute__((address_space(3))) u32*)l, 16, 0, 0);
}

#define MFMA32(A, B, C) __builtin_amdgcn_mfma_f32_16x16x32_f16((A), (B), (C), 0, 0, 0)
#define MFMA16(A, B, C) __builtin_amdgcn_mfma_f32_16x16x16f16((A), (B), (C), 0, 0, 0)

// K1: M[c][cp] = sum_o w1[o,c]*w2[o,cp] ; g[cp] = sum_o b1[o]*w2[o,cp]
__global__ void k_prep(const float* __restrict__ w1, const float* __restrict__ w2,
                       const float* __restrict__ b1, float* __restrict__ M,
                       float* __restrict__ g) {
  const int c  = blockIdx.x;
  const int cp = threadIdx.x;
  float acc = 0.f;
#pragma unroll 8
  for (int o = 0; o < CC; ++o)
    acc += w1[o * CC + c] * w2[o * CC + cp];
  M[c * CC + cp] = acc;
  if (c == 0) {
    float ga = 0.f;
    for (int o = 0; o < CC; ++o)
      ga += b1[o] * w2[o * CC + cp];
    g[cp] = ga;
  }
}

// K-cvt: x2 tile -> kimg (swizzled [j][c] LDS byte-image) + vimg (PV-fragment
// order) + r2[b,j] = sum_c g[c]*x2[b,c,j].   (all fp16 RNE)
// K image row j (512B): 16B slot st holds halves c=8s..8s+7 with s = st^(j&7).
__global__ void k_cvt(const float* __restrict__ x2, const float* __restrict__ g,
                      ush* __restrict__ kimg, ush* __restrict__ vimg,
                      float* __restrict__ r2) {
  __shared__ float Xs[256 * 37];
  __shared__ float Ps[32 * 9];
  const int tid = threadIdx.x;
  const int b   = blockIdx.x >> 7;
  const int jt  = blockIdx.x & 127;
  const int j0  = jt << 5;
  const float* x2b = x2 + ((size_t)b << 20);
  {
    const int jf = tid & 7, c0 = tid >> 3;
#pragma unroll
    for (int m = 0; m < 8; ++m) {
      int c = c0 + (m << 5);
      float4 v = *(const float4*)(x2b + ((size_t)c << 12) + j0 + (jf << 2));
      *(float4*)(Xs + c * 37 + (jf << 2)) = v;
    }
  }
  __syncthreads();
  const size_t tile = ((size_t)blockIdx.x) << 13;   // halves
  {
    ush* kp = kimg + tile;
#pragma unroll
    for (int m = 0; m < 4; ++m) {
      int idx = tid + (m << 8);
      int j = idx >> 5, st = idx & 31;
      int s = st ^ (j & 7);
      u32 hw[4];
#pragma unroll
      for (int k = 0; k < 4; ++k) {
        float a  = Xs[(8 * s + 2 * k) * 37 + j];
        float c2 = Xs[(8 * s + 2 * k + 1) * 37 + j];
        hw[k] = (u32)f2h(a) | ((u32)f2h(c2) << 16);
      }
      u32x4 v; v.x = hw[0]; v.y = hw[1]; v.z = hw[2]; v.w = hw[3];
      *(u32x4*)(kp + (idx << 3)) = v;
    }
  }
  {
    ush* vp = vimg + tile;
#pragma unroll
    for (int mm = 0; mm < 4; ++mm) {
      int e = tid + (mm << 8);
      int lqe = e & 15, ge = (e >> 4) & 3, he = (e >> 6) & 1, me = e >> 7;
      int c0 = lqe + (me << 5);
      int q0 = (he << 4) + (ge << 2);
      const float* r0 = Xs + c0 * 37 + q0;
      const float* r1 = Xs + (c0 + 16) * 37 + q0;
      u32x4 v;
      v.x = (u32)f2h(r0[0]) | ((u32)f2h(r0[1]) << 16);
      v.y = (u32)f2h(r0[2]) | ((u32)f2h(r0[3]) << 16);
      v.z = (u32)f2h(r1[0]) | ((u32)f2h(r1[1]) << 16);
      v.w = (u32)f2h(r1[2]) | ((u32)f2h(r1[3]) << 16);
      *(u32x4*)(vp + (e << 3)) = v;
    }
  }
  {
    const int j = tid & 31, s = tid >> 5;
    float acc = 0.f;
#pragma unroll 8
    for (int k = 0; k < 32; ++k)
      acc += g[(s << 5) + k] * Xs[((s << 5) + k) * 37 + j];
    Ps[j * 9 + s] = acc;
  }
  __syncthreads();
  if (tid < 32) {
    float a = 0.f;
#pragma unroll
    for (int s = 0; s < 8; ++s) a += Ps[tid * 9 + s];
    r2[(b << 12) + j0 + tid] = a;
  }
}

// K3: QT=32, 512-thread blocks: 8 waves = (p:2 i) x (q:2 c) x (h:2 j).
// Producer/consumer: q=0 waves compute S+softmax ONCE, publish P-fragment +
// scl via LDS; q=1 waves consume P and do PV on their c-half. No duplicated
// work, vacc[8] keeps regs <=128 -> 4 waves/SIMD (16 waves/CU).
__launch_bounds__(512, 4)
__global__ void k_attn(const float* __restrict__ x1, const ush* __restrict__ kimg,
                       const ush* __restrict__ vimg, const float* __restrict__ M,
                       const float* __restrict__ r2, float* __restrict__ out) {
  extern __shared__ ush lds[];
  const int tid  = threadIdx.x;
  const int lane = tid & 63;
  const int w    = tid >> 6;
  const int h    = w & 1;          // j-group
  const int q    = (w >> 1) & 1;   // c-group (0 = producer)
  const int p    = w >> 2;         // i-group
  const int g    = lane >> 4;
  const int lq   = lane & 15;
  const int phb  = ((p << 1) + h) << 6;     // P/scl buffer base (per (p,h) pair)

  int bid = (int)blockIdx.x;
  bid = (bid & 7) * 64 + (bid >> 3);        // bijective XCD swizzle (512 = 8*64)
  const int b  = bid >> 7;
  const int i0 = (bid & 127) << 5;

  const float* x1b = x1 + ((size_t)b << 20);

  // ---- Q-prep (VALU f32, two 16-i passes); x1f @0 (18KB), Qhi @ byte 18432 ----
  float* x1f = (float*)lds;                 // [256][18] f32
  ush* Qhi = lds + 9216;                    // [32][256] halves (byte 18432..34816)
  for (int ih = 0; ih < 2; ++ih) {
    {
      const int jf = tid & 3, c0 = tid >> 2;
#pragma unroll
      for (int m = 0; m < 2; ++m) {
        int c = c0 + (m << 7);
        float4 v = *(const float4*)(x1b + ((size_t)c << 12) + i0 + (ih << 4) + (jf << 2));
        *(float4*)(x1f + c * 18 + (jf << 2)) = v;
      }
    }
    __syncthreads();
    {
      const int tc = tid & 63, iq = tid >> 6;   // i = 16ih + 2iq + e
      float acc[4][2];
#pragma unroll
      for (int a = 0; a < 4; ++a) { acc[a][0] = 0.f; acc[a][1] = 0.f; }
#pragma unroll 4
      for (int c = 0; c < CC; ++c) {
        float4 mv = *(const float4*)(M + c * CC + (tc << 2));
        float x0  = x1f[c * 18 + (iq << 1)];
        float x1v = x1f[c * 18 + (iq << 1) + 1];
        acc[0][0] += mv.x * x0; acc[0][1] += mv.x * x1v;
        acc[1][0] += mv.y * x0; acc[1][1] += mv.y * x1v;
        acc[2][0] += mv.z * x0; acc[2][1] += mv.z * x1v;
        acc[3][0] += mv.w * x0; acc[3][1] += mv.w * x1v;
      }
#pragma unroll
      for (int e = 0; e < 2; ++e) {
        int i = (ih << 4) + (iq << 1) + e;
        u32 h0 = (u32)f2h(acc[0][e]) | ((u32)f2h(acc[1][e]) << 16);
        u32 h1 = (u32)f2h(acc[2][e]) | ((u32)f2h(acc[3][e]) << 16);
        u32x2 hw; hw.x = h0; hw.y = h1;
        *(u32x2*)(Qhi + (i << 8) + (tc << 2)) = hw;
      }
    }
    __syncthreads();
  }

  // ---- preload Q fragments (producers only) ----
  Frag8 QBh[8];
  if (q == 0) {
    const int qoff = ((p << 4) + lq) << 8;
#pragma unroll
    for (int cs = 0; cs < 8; ++cs)
      QBh[cs].u4 = *(const u32x4*)(Qhi + qoff + (cs << 5) + (g << 3));
  }
  __syncthreads();

  // ---- main flash loop ----
  f32x4 vacc[8];
#pragma unroll
  for (int n = 0; n < 8; ++n) vacc[n] = (f32x4){0.f, 0.f, 0.f, 0.f};
  float m_run = -3.0e38f, l_run = 0.f;

  const int sx   = lq & 7;
  const int koff = ((h << 4) + lq) << 8;    // K row (halves)
  const float* r2p = r2 + (b << 12) + (h << 4) + (g << 2);
  const size_t bt = (size_t)(b << 7);
  const ush* vbase = vimg + (bt << 13) + (q << 12) + (h << 9) + (g << 7) + (lq << 3);

  u32x2* Pb  = (u32x2*)(lds + 16384);       // byte 32768: [4 ph][64 lane] x 8B
  float* Scf = (float*)(lds + 17408);       // byte 34816: [4 ph][64 lane] x 4B

  Frag8 Vd[4];
  float4 r2a, r2b;

  // prologue: K(0) DMA (2/thread), V(0) 4 loads, r2(0) (producers).
  {
    const ush* gk = kimg + (bt << 13);
    gload16(gk + ((size_t)tid << 3),         lds + (tid << 3));
    gload16(gk + ((size_t)(tid + 512) << 3), lds + ((tid + 512) << 3));
    __builtin_amdgcn_sched_barrier(0);
#pragma unroll
    for (int m = 0; m < 4; ++m)
      Vd[m].u4 = *(const u32x4*)(vbase + (m << 10));
    if (q == 0) r2a = *(const float4*)(r2p);
  }
  __builtin_amdgcn_sched_barrier(0);
  if (q == 0) asm volatile("s_waitcnt vmcnt(5)" ::: "memory");
  else        asm volatile("s_waitcnt vmcnt(4)" ::: "memory");
  __builtin_amdgcn_sched_barrier(0);
  __builtin_amdgcn_s_barrier();

  auto body = [&](int t, float4& r2c, float4& r2n) {
    const int cur = (t & 1) << 13;
    if (t + 1 < 128) {
      const int nxt = cur ^ 8192;
      const ush* gk = kimg + ((bt + t + 1) << 13);
      gload16(gk + ((size_t)tid << 3),         lds + nxt + (tid << 3));
      gload16(gk + ((size_t)(tid + 512) << 3), lds + nxt + ((tid + 512) << 3));
    }
    __builtin_amdgcn_sched_barrier(0);

    float scl;
    Frag4 Pf;
    if (q == 0) {
      // ---- producer: S = K·Q once, softmax, publish P + scl ----
      const ush* kb = lds + cur;
      f32x4 a1 = {0.f,0.f,0.f,0.f}, a2 = {0.f,0.f,0.f,0.f};
#pragma unroll
      for (int cs = 0; cs < 8; cs += 2) {
        int st1 = ((cs << 2) + g) ^ sx;
        int st2 = (((cs + 1) << 2) + g) ^ sx;
        Frag8 A1; A1.u4 = *(const u32x4*)(kb + koff + (st1 << 3));
        Frag8 A2; A2.u4 = *(const u32x4*)(kb + koff + (st2 << 3));
        a1 = MFMA32(A1.f, QBh[cs].f, a1);
        a2 = MFMA32(A2.f, QBh[cs + 1].f, a2);
      }
      if (t + 1 < 128) asm volatile("s_waitcnt vmcnt(2)" ::: "memory");
      else             asm volatile("s_waitcnt vmcnt(0)" ::: "memory");
      __builtin_amdgcn_sched_barrier(0);

      float s0 = a1[0] + a2[0] + r2c.x, s1 = a1[1] + a2[1] + r2c.y;
      float s2 = a1[2] + a2[2] + r2c.z, s3 = a1[3] + a2[3] + r2c.w;
      float mx = fmaxf(fmaxf(s0, s1), fmaxf(s2, s3));
      mx = fmaxf(mx, __shfl_xor(mx, 16));
      mx = fmaxf(mx, __shfl_xor(mx, 32));
      float mn = fmaxf(m_run, mx);
      scl = __expf(m_run - mn);
      float p0 = __expf(s0 - mn), p1 = __expf(s1 - mn);
      float p2 = __expf(s2 - mn), p3 = __expf(s3 - mn);
      float rs = p0 + p1 + p2 + p3;
      rs += __shfl_xor(rs, 16);
      rs += __shfl_xor(rs, 32);
      l_run = l_run * scl + rs;
      m_run = mn;
      Pf.u2.x = pkrtz(p0, p1);
      Pf.u2.y = pkrtz(p2, p3);
      Pb[phb + lane] = Pf.u2;
      Scf[phb + lane] = scl;
      asm volatile("s_waitcnt lgkmcnt(0)" ::: "memory");
    } else {
      if (t + 1 < 128) asm volatile("s_waitcnt vmcnt(2)" ::: "memory");
      else             asm volatile("s_waitcnt vmcnt(0)" ::: "memory");
    }
    __builtin_amdgcn_sched_barrier(0);
    __builtin_amdgcn_s_barrier();          // P + scl visible

    if (q == 1) {
      Pf.u2 = Pb[phb + lane];
      scl   = Scf[phb + lane];
    }

    if (!__all(scl == 1.0f)) {
#pragma unroll
      for (int n = 0; n < 8; ++n) {
        vacc[n][0] *= scl; vacc[n][1] *= scl;
        vacc[n][2] *= scl; vacc[n][3] *= scl;
      }
    }
#pragma unroll
    for (int m = 0; m < 4; ++m) {
      Frag4 Va, Vb;
      Va.u2.x = Vd[m].u4.x; Va.u2.y = Vd[m].u4.y;     // n = 2m
      Vb.u2.x = Vd[m].u4.z; Vb.u2.y = Vd[m].u4.w;     // n = 2m+1
      vacc[2 * m]     = MFMA16(Va.f, Pf.f, vacc[2 * m]);
      vacc[2 * m + 1] = MFMA16(Vb.f, Pf.f, vacc[2 * m + 1]);
    }

    if (t + 1 < 128) {
      const ush* vt_ = vbase + ((size_t)(t + 1) << 13);
#pragma unroll
      for (int m = 0; m < 4; ++m)
        Vd[m].u4 = *(const u32x4*)(vt_ + (m << 10));
      if (q == 0) r2n = *(const float4*)(r2p + ((t + 1) << 5));
      __builtin_amdgcn_sched_barrier(0);
      if (q == 0) asm volatile("s_waitcnt vmcnt(5)" ::: "memory");
      else        asm volatile("s_waitcnt vmcnt(4)" ::: "memory");
      __builtin_amdgcn_sched_barrier(0);
      __builtin_amdgcn_s_barrier();        // kb[nxt] ready, P consumed
    }
  };

  for (int tt = 0; tt < 128; tt += 2) {
    body(tt,     r2a, r2b);
    body(tt + 1, r2b, r2a);
  }

  // ---- merge j-halves, normalize, store ----
  __syncthreads();
  float* Cmb = (float*)lds;                 // [2 p][256 c][17] f32 = 34816B
  float* Msm = (float*)(lds + 17408);       // byte 34816: [2 p][2 h][16]
  float* Lsm = Msm + 64;
  if (q == 0 && g == 0) {
    Msm[p * 32 + h * 16 + lq] = m_run;
    Lsm[p * 32 + h * 16 + lq] = l_run;
  }
  __syncthreads();
  float m_own = (q == 0) ? m_run : Msm[p * 32 + h * 16 + lq];
  float l_own = (q == 0) ? l_run : Lsm[p * 32 + h * 16 + lq];
  float mo  = Msm[p * 32 + (1 - h) * 16 + lq];
  float lo2 = Lsm[p * 32 + (1 - h) * 16 + lq];
  float mt    = fmaxf(m_own, mo);
  float aSelf = __expf(m_own - mt);
  float l_tot = l_own * aSelf + lo2 * __expf(mo - mt);

  if (h == 0) {
    float* cb_ = Cmb + p * (CC * RSC);
#pragma unroll
    for (int n = 0; n < 8; ++n)
#pragma unroll
      for (int r = 0; r < 4; ++r) {
        int c = (q << 7) + (n << 4) + (g << 2) + r;
        cb_[c * RSC + lq] = vacc[n][r] * aSelf;
      }
  }
  __syncthreads();
  if (h == 1) {
    const float* cb_ = Cmb + p * (CC * RSC);
    float inv = 1.f / l_tot;
    float* ob = out + ((size_t)b << 20) + i0 + (p << 4) + lq;
#pragma unroll
    for (int n = 0; n < 8; ++n)
#pragma unroll
      for (int r = 0; r < 4; ++r) {
        int c = (q << 7) + (n << 4) + (g << 2) + r;
        ob[(size_t)c << 12] = (vacc[n][r] * aSelf + cb_[c * RSC + lq]) * inv;
      }
  }
}

extern "C" void kernel_launch(void* const* d_in, const int* in_sizes, int n_in,
                              void* d_out, int out_size, void* d_ws, size_t ws_size,
                              hipStream_t stream) {
  const float* x1 = (const float*)d_in[0];
  const float* x2 = (const float*)d_in[1];
  const float* w1 = (const float*)d_in[2];
  const float* b1 = (const float*)d_in[3];
  const float* w2 = (const float*)d_in[4];
  // b2 (d_in[5]) contributes only row-constant energy terms -> cancels in softmax.

  float* M  = (float*)d_ws;            // 256KB
  float* g  = M + 65536;
  float* r2 = g + 256;                 // 64KB
  ush* kimg = (ush*)(r2 + 16384);      // 8MB, per-tile 16KB LDS byte-images
  ush* vimg = kimg + 4194304;          // 8MB, per-tile PV-fragment-ordered fp16
  float* outp = (float*)d_out;

  const int LDS_BYTES = 35840;
  (void)hipFuncSetAttribute((const void*)k_attn,
                            hipFuncAttributeMaxDynamicSharedMemorySize, LDS_BYTES);

  k_prep<<<CC, 256, 0, stream>>>(w1, w2, b1, M, g);
  k_cvt<<<BB * (NN / 32), 256, 0, stream>>>(x2, g, kimg, vimg, r2);
  k_attn<<<BB * (NN / 32), 512, LDS_BYTES, stream>>>(x1, kimg, vimg, M, r2, outp);
  (void)in_sizes; (void)n_in; (void)out_size; (void)ws_size;
}